// Round 23
// baseline (223.028 us; speedup 1.0000x reference)
//
#include <hip/hip_runtime.h>
#include <hip/hip_bf16.h>
#include <math.h>

// ---------------------------------------------------------------------------
// Transformer block forward (pre-LN), B=2 T=2048 D=1024 H=16 DH=64.
// R22->R23: QKV moved onto the verified 8-phase 256x256 gemm256_bt (the
// structure that gives FFN1 ~1.15 PF, 1.8x the 2-phase kernels' per-FLOP
// rate). Templated MODE: 1 = FFN1 (bias+ReLU->bf16, unchanged), 2 = QKV
// scatter (Q,K row-major; V transposed; no bias). Grid 16x12 = 192 blocks,
// one round, same K-loop (nk=16) as FFN1. Everything else byte-identical
// to the banked best (R18/R21 = 201.7/202.2us): prep_fused, attention v11
// (complementary-qt pairing), gemm_n64 proj/FFN2.
// x1 (fp32 residual) lives in d_out. Workspace layout (96 MB): see R4.
// ---------------------------------------------------------------------------

#define D_MODEL 1024
#define NH 16
#define DHEAD 64
#define SEQ 2048
#define NTOK 4096

typedef __bf16 bf16x8 __attribute__((ext_vector_type(8)));
typedef float f32x4 __attribute__((ext_vector_type(4)));
typedef float f32x16 __attribute__((ext_vector_type(16)));
typedef unsigned short u16x8 __attribute__((ext_vector_type(8)));

__device__ __forceinline__ unsigned short f2b(float f) {
  unsigned u = __builtin_bit_cast(unsigned, f);
  u = u + 0x7fffu + ((u >> 16) & 1u);          // round-nearest-even
  return (unsigned short)(u >> 16);
}

__device__ __forceinline__ bf16x8 ld_bf16x8(const unsigned short* p) {
  u16x8 u = *(const u16x8*)p;
  return __builtin_bit_cast(bf16x8, u);
}

// async global->LDS, 16B per lane; LDS dest is wave-uniform base + lane*16.
__device__ __forceinline__ void async16(void* lds, const void* g) {
  __builtin_amdgcn_global_load_lds(
      (const __attribute__((address_space(1))) unsigned int*)g,
      (__attribute__((address_space(3))) unsigned int*)lds, 16, 0, 0);
}

// inline-asm LDS ops: invisible to the compiler's waitcnt pass, so our
// counted vmcnt/lgkmcnt discipline is authoritative (R8 lesson).
__device__ __forceinline__ bf16x8 ds_read16(const void* p) {
  bf16x8 r;
  unsigned a = (unsigned)(size_t)(const __attribute__((address_space(3))) void*)p;
  asm volatile("ds_read_b128 %0, %1" : "=v"(r) : "v"(a));
  return r;
}
__device__ __forceinline__ void ds_write32(void* p, unsigned v) {
  unsigned a = (unsigned)(size_t)(__attribute__((address_space(3))) void*)p;
  asm volatile("ds_write_b32 %0, %1" :: "v"(a), "v"(v));
}
__device__ __forceinline__ unsigned cvt_pk_bf16(float lo, float hi) {
  unsigned d;
  asm("v_cvt_pk_bf16_f32 %0, %1, %2" : "=v"(d) : "v"(lo), "v"(hi));
  return d;
}
#define WAIT_LGKM0_FENCE() do { \
  asm volatile("s_waitcnt lgkmcnt(0)" ::: "memory"); \
  __builtin_amdgcn_sched_barrier(0); } while (0)
#define WAIT_LGKM8_FENCE() do { \
  asm volatile("s_waitcnt lgkmcnt(8)" ::: "memory"); \
  __builtin_amdgcn_sched_barrier(0); } while (0)

// ---------------------------------------------------------------------------
// prep_fused: [0,768) repack_qkv | [768,1024) w_proj^T | [1024,2048) w1^T |
// [2048,3072) w2^T | [3072,7168) LN1. R18-verified.
// ---------------------------------------------------------------------------
__global__ __launch_bounds__(256) void prep_fused(
    const float* __restrict__ wq, const float* __restrict__ wk,
    const float* __restrict__ wv, const float* __restrict__ w_proj,
    const float* __restrict__ w1, const float* __restrict__ w2,
    const float* __restrict__ x, const float* __restrict__ ln1g,
    const float* __restrict__ ln1b,
    unsigned short* __restrict__ WqkvT, unsigned short* __restrict__ wprojT,
    unsigned short* __restrict__ w1T, unsigned short* __restrict__ w2T,
    unsigned short* __restrict__ xn) {
  __shared__ float tile[64][65];
  __shared__ float ps[4], ps2[4];
  const int bid = blockIdx.x;
  const int tidx = threadIdx.x;

  if (bid < 3072) {
    const float* in;
    unsigned short* outp;
    int r0, c0, R, C;
    if (bid < 768) {
      int t = bid;
      int sel = t >> 8, hh = (t >> 4) & 15, rt = t & 15;
      in = (sel == 0 ? wq : sel == 1 ? wk : wv) + (size_t)hh * D_MODEL * DHEAD;
      int d0 = rt * 64;
      for (int i = 0; i < 16; i++) {
        int idx = i * 256 + tidx;
        int r = idx >> 6, c = idx & 63;
        tile[r][c] = in[(size_t)(d0 + r) * DHEAD + c];
      }
      __syncthreads();
      unsigned short* ob = WqkvT + (size_t)(sel * 1024 + hh * 64) * D_MODEL + d0;
      for (int i = 0; i < 16; i++) {
        int idx = i * 256 + tidx;
        int c = idx >> 6, r = idx & 63;
        ob[(size_t)c * D_MODEL + r] = f2b(tile[r][c]);
      }
      return;
    } else if (bid < 1024) {
      int t = bid - 768;                       // 16x16
      in = w_proj; outp = wprojT; R = 1024; C = 1024;
      r0 = (t & 15) * 64; c0 = (t >> 4) * 64;
    } else if (bid < 2048) {
      int t = bid - 1024;                      // 16x64
      in = w1; outp = w1T; R = 1024; C = 4096;
      r0 = (t & 15) * 64; c0 = (t >> 4) * 64;
    } else {
      int t = bid - 2048;                      // 64x16
      in = w2; outp = w2T; R = 4096; C = 1024;
      r0 = (t & 63) * 64; c0 = (t >> 6) * 64;
    }
    for (int i = 0; i < 16; i++) {
      int idx = i * 256 + tidx;
      int r = idx >> 6, c = idx & 63;
      tile[r][c] = in[(size_t)(r0 + r) * C + c0 + c];
    }
    __syncthreads();
    for (int i = 0; i < 16; i++) {
      int idx = i * 256 + tidx;
      int c = idx >> 6, r = idx & 63;
      outp[(size_t)(c0 + c) * R + r0 + r] = f2b(tile[r][c]);
    }
    return;
  }

  // ---- LN1: one block per row
  const int row = bid - 3072;
  const float4* xr = (const float4*)(x + (size_t)row * D_MODEL);
  float4 v = xr[tidx];
  float s = v.x + v.y + v.z + v.w;
  float s2 = v.x * v.x + v.y * v.y + v.z * v.z + v.w * v.w;
  for (int m = 1; m < 64; m <<= 1) {
    s += __shfl_xor(s, m);
    s2 += __shfl_xor(s2, m);
  }
  int wid = tidx >> 6;
  if ((tidx & 63) == 0) { ps[wid] = s; ps2[wid] = s2; }
  __syncthreads();
  float S = ps[0] + ps[1] + ps[2] + ps[3];
  float S2 = ps2[0] + ps2[1] + ps2[2] + ps2[3];
  float mu = S * (1.f / D_MODEL);
  float var = S2 * (1.f / D_MODEL) - mu * mu;
  float inv = rsqrtf(var + 1e-5f);
  float4 gv = ((const float4*)ln1g)[tidx];
  float4 bv = ((const float4*)ln1b)[tidx];
  ushort4 o;
  o.x = f2b((v.x - mu) * inv * gv.x + bv.x);
  o.y = f2b((v.y - mu) * inv * gv.y + bv.y);
  o.z = f2b((v.z - mu) * inv * gv.z + bv.z);
  o.w = f2b((v.w - mu) * inv * gv.w + bv.w);
  ((ushort4*)(xn + (size_t)row * D_MODEL))[tidx] = o;
}

// ---------------------------------------------------------------------------
// LayerNorm: fp32 [rows][1024] -> bf16, one block per row (LN2).
// ---------------------------------------------------------------------------
__global__ __launch_bounds__(256) void layernorm_bf16(
    const float* __restrict__ x, const float* __restrict__ g,
    const float* __restrict__ bta, unsigned short* __restrict__ out) {
  int row = blockIdx.x;
  int tid = threadIdx.x;
  const float4* xr = (const float4*)(x + (size_t)row * D_MODEL);
  float4 v = xr[tid];
  float s = v.x + v.y + v.z + v.w;
  float s2 = v.x * v.x + v.y * v.y + v.z * v.z + v.w * v.w;
  for (int m = 1; m < 64; m <<= 1) {
    s += __shfl_xor(s, m);
    s2 += __shfl_xor(s2, m);
  }
  __shared__ float ps[4], ps2[4];
  int wid = tid >> 6;
  if ((tid & 63) == 0) { ps[wid] = s; ps2[wid] = s2; }
  __syncthreads();
  float S = ps[0] + ps[1] + ps[2] + ps[3];
  float S2 = ps2[0] + ps2[1] + ps2[2] + ps2[3];
  float mu = S * (1.f / D_MODEL);
  float var = S2 * (1.f / D_MODEL) - mu * mu;
  float inv = rsqrtf(var + 1e-5f);
  float4 gv = ((const float4*)g)[tid];
  float4 bv = ((const float4*)bta)[tid];
  ushort4 o;
  o.x = f2b((v.x - mu) * inv * gv.x + bv.x);
  o.y = f2b((v.y - mu) * inv * gv.y + bv.y);
  o.z = f2b((v.z - mu) * inv * gv.z + bv.z);
  o.w = f2b((v.w - mu) * inv * gv.w + bv.w);
  ((ushort4*)(out + (size_t)row * D_MODEL))[tid] = o;
}

// ---------------------------------------------------------------------------
// GEMM 128x64, 4 waves (2Mx2N, wave tile 64x32), pipelined (2 LDS bufs,
// counted vmcnt(6), asm ds_read). 48KB LDS -> 3 blocks/CU (R17-verified).
// For proj (TAG 0) and FFN2 (TAG 1). Epilogue: outF = acc + bias + resid.
// ---------------------------------------------------------------------------
template <int TAG>
__global__ __launch_bounds__(256, 3) void gemm_n64(
    const unsigned short* __restrict__ A, const unsigned short* __restrict__ BT,
    int M, int N, int K,
    const float* __restrict__ bias, const float* __restrict__ resid,
    float* __restrict__ outF) {
  __shared__ alignas(16) unsigned short lsA[2][128 * 64];   // 16KB each
  __shared__ alignas(16) unsigned short lsB[2][64 * 64];    // 8KB each
  const int tid = threadIdx.x;
  const int wid = tid >> 6, lane = tid & 63;
  const int lr = lane & 15, lg = lane >> 4;
  const int row0 = blockIdx.x * 128, col0 = blockIdx.y * 64;
  const int wr = (wid >> 1) * 64, wc = (wid & 1) * 32;
  f32x4 acc[4][2] = {};
  const int nk = K >> 6;

  auto STAGE = [&](int bi, int kt) {
    const int k0 = kt << 6;
#pragma unroll
    for (int i = 0; i < 4; i++) {      // A: 1024 slots of 16B
      int sidx = i * 256 + tid;
      int r = sidx >> 3, s = sidx & 7;
      int ss = s ^ (r & 7);
      async16((char*)lsA[bi] + (i * 256 + wid * 64) * 16,
              A + (size_t)(row0 + r) * K + k0 + ss * 8);
    }
#pragma unroll
    for (int i = 0; i < 2; i++) {      // B: 512 slots of 16B
      int sidx = i * 256 + tid;
      int r = sidx >> 3, s = sidx & 7;
      int ss = s ^ (r & 7);
      async16((char*)lsB[bi] + (i * 256 + wid * 64) * 16,
              BT + (size_t)(col0 + r) * K + k0 + ss * 8);
    }
  };

  STAGE(0, 0);
  for (int kt = 0; kt < nk; ++kt) {
    const int cur = kt & 1;
    if (kt + 1 < nk) {
      STAGE(cur ^ 1, kt + 1);
      asm volatile("s_waitcnt vmcnt(6)" ::: "memory");   // drain tile kt's 6 only
    } else {
      asm volatile("s_waitcnt vmcnt(0)" ::: "memory");
    }
    __builtin_amdgcn_s_barrier();
    __builtin_amdgcn_sched_barrier(0);
#pragma unroll
    for (int kk = 0; kk < 2; ++kk) {
      bf16x8 af[4], bfr[2];
#pragma unroll
      for (int m = 0; m < 4; m++) {
        int r = wr + m * 16 + lr;
        int sw = (kk * 4 + lg) ^ (r & 7);
        af[m] = ds_read16((const char*)lsA[cur] + r * 128 + sw * 16);
      }
#pragma unroll
      for (int n = 0; n < 2; n++) {
        int r = wc + n * 16 + lr;
        int sw = (kk * 4 + lg) ^ (r & 7);
        bfr[n] = ds_read16((const char*)lsB[cur] + r * 128 + sw * 16);
      }
      WAIT_LGKM0_FENCE();
      __builtin_amdgcn_s_setprio(1);
#pragma unroll
      for (int m = 0; m < 4; m++)
#pragma unroll
        for (int n = 0; n < 2; n++)
          acc[m][n] = __builtin_amdgcn_mfma_f32_16x16x32_bf16(af[m], bfr[n], acc[m][n], 0, 0, 0);
      __builtin_amdgcn_s_setprio(0);
    }
    __builtin_amdgcn_sched_barrier(0);
    __builtin_amdgcn_s_barrier();      // all done reading buf[cur] before restage
  }
#pragma unroll
  for (int m = 0; m < 4; m++) {
#pragma unroll
    for (int n = 0; n < 2; n++) {
#pragma unroll
      for (int r2 = 0; r2 < 4; r2++) {
        int row = row0 + wr + m * 16 + lg * 4 + r2;
        int col = col0 + wc + n * 16 + lr;
        float v = acc[m][n][r2] + bias[col] + resid[(size_t)row * N + col];
        outF[(size_t)row * N + col] = v;
      }
    }
  }
}

// ---------------------------------------------------------------------------
// GEMM 256x256, 8-phase (T3+T4+T5). MODE 1: FFN1 (bias+ReLU -> bf16).
// MODE 2: QKV scatter (Q,K -> [b][h][t][dh]; V -> [b][h][dh][t]; no bias).
// asm fragment reads, counted vmcnt — R8/R9-verified structure.
// ---------------------------------------------------------------------------
template <int MODE>
__global__ __launch_bounds__(512, 2) void gemm256_bt(
    const unsigned short* __restrict__ A, const unsigned short* __restrict__ BT,
    int M, int N, int K, int ntn,
    const float* __restrict__ bias, unsigned short* __restrict__ outB,
    unsigned short* __restrict__ outQ, unsigned short* __restrict__ outK,
    unsigned short* __restrict__ outV) {
  __shared__ alignas(16) unsigned short ls[2][2][2][256 * 32];
  const int tid = threadIdx.x;
  const int wid = tid >> 6, lane = tid & 63;
  const int lr = lane & 15, lg = lane >> 4;
  const int nwg = gridDim.x;
  const int wg = (blockIdx.x & 7) * (nwg >> 3) + (blockIdx.x >> 3);
  const int row0 = (wg / ntn) * 256, col0 = (wg % ntn) * 256;
  const int mbase = (wid >> 2) * 128;
  const int nbase = (wid & 3) * 64;

  f32x4 acc[8][4] = {};

  auto STAGE = [&](int buf, int kh, int ab, int kt) {
    const unsigned short* src = ab ? (BT + (size_t)col0 * K) : (A + (size_t)row0 * K);
    const int kbase = kt * 64 + kh * 32;
    unsigned short* dst0 = &ls[buf][kh][ab][0];
#pragma unroll
    for (int c = 0; c < 2; c++) {
      int s = c * 512 + tid;
      int row = s >> 2, c2 = s & 3;
      int ss = c2 ^ ((row >> 1) & 3);
      async16(dst0 + (size_t)(c * 512 + wid * 64) * 8,
              src + (size_t)row * K + kbase + ss * 8);
    }
  };
  auto LDA = [&](bf16x8* a, int buf, int kk, int mh) {
#pragma unroll
    for (int i = 0; i < 4; i++) {
      int mrow = mbase + (mh * 4 + i) * 16 + lr;
      int ch = lg ^ ((mrow >> 1) & 3);
      a[i] = ds_read16(&ls[buf][kk][0][mrow * 32 + ch * 8]);
    }
  };
  auto LDB = [&](bf16x8* b, int buf, int kk) {
#pragma unroll
    for (int i = 0; i < 4; i++) {
      int brow = nbase + i * 16 + lr;
      int ch = lg ^ ((brow >> 1) & 3);
      b[i] = ds_read16(&ls[buf][kk][1][brow * 32 + ch * 8]);
    }
  };

  const int nk = K >> 6;
  STAGE(0, 0, 0, 0); STAGE(0, 0, 1, 0); STAGE(0, 1, 0, 0); STAGE(0, 1, 1, 0);
  asm volatile("s_waitcnt vmcnt(4)" ::: "memory");
  __builtin_amdgcn_s_barrier();

  for (int t = 0; t < nk; ++t) {
    const int cur = t & 1, nxt = cur ^ 1;
    const bool haveNext = (t + 1 < nk);
    bf16x8 a[4], b[4];
    // ---- ph1
    LDA(a, cur, 0, 0); LDB(b, cur, 0);
    if (haveNext) STAGE(nxt, 0, 0, t + 1);
    __builtin_amdgcn_s_barrier();
    WAIT_LGKM0_FENCE();
    __builtin_amdgcn_s_setprio(1);
#pragma unroll
    for (int i = 0; i < 4; i++)
#pragma unroll
      for (int j = 0; j < 4; j++)
        acc[i][j] = __builtin_amdgcn_mfma_f32_16x16x32_bf16(a[i], b[j], acc[i][j], 0, 0, 0);
    __builtin_amdgcn_s_setprio(0);
    __builtin_amdgcn_s_barrier();
    // ---- ph2
    LDA(a, cur, 0, 1);
    if (haveNext) {
      STAGE(nxt, 0, 1, t + 1);
      asm volatile("s_waitcnt vmcnt(4)" ::: "memory");
    } else {
      asm volatile("s_waitcnt vmcnt(0)" ::: "memory");
    }
    __builtin_amdgcn_s_barrier();
    WAIT_LGKM0_FENCE();
    __builtin_amdgcn_s_setprio(1);
#pragma unroll
    for (int i = 0; i < 4; i++)
#pragma unroll
      for (int j = 0; j < 4; j++)
        acc[4 + i][j] = __builtin_amdgcn_mfma_f32_16x16x32_bf16(a[i], b[j], acc[4 + i][j], 0, 0, 0);
    __builtin_amdgcn_s_setprio(0);
    __builtin_amdgcn_s_barrier();
    // ---- ph3
    LDA(a, cur, 1, 0); LDB(b, cur, 1);
    if (haveNext) STAGE(nxt, 1, 0, t + 1);
    __builtin_amdgcn_s_barrier();
    WAIT_LGKM0_FENCE();
    __builtin_amdgcn_s_setprio(1);
#pragma unroll
    for (int i = 0; i < 4; i++)
#pragma unroll
      for (int j = 0; j < 4; j++)
        acc[i][j] = __builtin_amdgcn_mfma_f32_16x16x32_bf16(a[i], b[j], acc[i][j], 0, 0, 0);
    __builtin_amdgcn_s_setprio(0);
    __builtin_amdgcn_s_barrier();
    // ---- ph4
    LDA(a, cur, 1, 1);
    if (haveNext) {
      STAGE(nxt, 1, 1, t + 1);
      asm volatile("s_waitcnt vmcnt(4)" ::: "memory");
    }
    __builtin_amdgcn_s_barrier();
    WAIT_LGKM0_FENCE();
    __builtin_amdgcn_s_setprio(1);
#pragma unroll
    for (int i = 0; i < 4; i++)
#pragma unroll
      for (int j = 0; j < 4; j++)
        acc[4 + i][j] = __builtin_amdgcn_mfma_f32_16x16x32_bf16(a[i], b[j], acc[4 + i][j], 0, 0, 0);
    __builtin_amdgcn_s_setprio(0);
    __builtin_amdgcn_s_barrier();
  }
#pragma unroll
  for (int mi = 0; mi < 8; mi++) {
#pragma unroll
    for (int ni = 0; ni < 4; ni++) {
#pragma unroll
      for (int r2 = 0; r2 < 4; r2++) {
        int row = row0 + mbase + mi * 16 + lg * 4 + r2;
        int col = col0 + nbase + ni * 16 + lr;
        float v = acc[mi][ni][r2];
        if constexpr (MODE == 1) {
          v += bias[col];
          outB[(size_t)row * N + col] = f2b(fmaxf(v, 0.f));
        } else {
          int sel = col >> 10, jj = col & 1023, hh = jj >> 6, dh = jj & 63;
          int b2 = row >> 11, tt = row & 2047;
          size_t bh = (size_t)(b2 * NH + hh);
          if (sel == 0)      outQ[(bh * SEQ + tt) * DHEAD + dh] = f2b(v);
          else if (sel == 1) outK[(bh * SEQ + tt) * DHEAD + dh] = f2b(v);
          else               outV[(bh * DHEAD + dh) * SEQ + tt] = f2b(v);  // transposed
        }
      }
    }
  }
}

// ---------------------------------------------------------------------------
// Causal flash attention v11 (R16/R18-verified): 128-key intervals, group
// pipelining, split accumulators, complementary-qt CU pairing. NO setprio.
// ---------------------------------------------------------------------------

// read group G's K/V fragments into KF[4], VF[4]
#define ATTN_READS(KF, VF, G) do {                                          \
  int krow_ = 32 * (G) + l31;                                               \
  int ksw_ = krow_ & 7;                                                     \
  _Pragma("unroll")                                                         \
  for (int dk_ = 0; dk_ < 4; dk_++) {                                       \
    int ch_ = (2 * dk_ + h) ^ ksw_;                                         \
    KF[dk_] = ds_read16((const char*)Kc + krow_ * 128 + ch_ * 16);          \
  }                                                                         \
  _Pragma("unroll")                                                         \
  for (int dg_ = 0; dg_ < 2; dg_++) {                                       \
    int vrow_ = 32 * dg_ + l31;                                             \
    int vsw_ = vrow_ & 7;                                                   \
    _Pragma("unroll")                                                       \
    for (int c_ = 0; c_ < 2; c_++) {                                        \
      int kk_ = 2 * (G) + c_;                                               \
      int ch_ = (2 * kk_ + h) ^ vsw_;                                       \
      VF[dg_ * 2 + c_] = ds_read16((const char*)Vc + vrow_ * 256 + ch_ * 16); \
    }                                                                       \
  }                                                                         \
} while (0)

// compute group G from KF/VF into accumulators OA(d0-31)/OB(d32-63)
#define ATTN_COMPUTE(KF, VF, G, OA, OB) do {                                \
  const int s0g_ = s0 + 32 * (G);                                           \
  const bool needMask_ = (s0g_ == q0w);                                     \
  f32x16 st_ = {};                                                          \
  _Pragma("unroll")                                                         \
  for (int dk_ = 0; dk_ < 4; dk_++)                                         \
    st_ = __builtin_amdgcn_mfma_f32_32x32x16_bf16(KF[dk_], qf[dk_], st_, 0, 0, 0); \
  float p_[16];                                                             \
  _Pragma("unroll")                                                         \
  for (int reg_ = 0; reg_ < 16; reg_++) {                                   \
    float xx_ = st_[reg_] * cs;                                             \
    if (needMask_) {                                                        \
      int kg_ = s0g_ + (reg_ & 3) + 8 * (reg_ >> 2) + 4 * h;                \
      if (kg_ > q0w + l31) xx_ = -INFINITY;                                 \
    }                                                                       \
    float e_ = __builtin_amdgcn_exp2f(xx_);                                 \
    p_[reg_] = e_;                                                          \
    psum4[reg_ & 3] += e_;                                                  \
  }                                                                         \
  unsigned w_[8];                                                           \
  _Pragma("unroll")                                                         \
  for (int s_ = 0; s_ < 4; s_++) {                                          \
    w_[s_ * 2 + 0] = cvt_pk_bf16(p_[s_ * 4 + 0], p_[s_ * 4 + 1]);           \
    w_[s_ * 2 + 1] = cvt_pk_bf16(p_[s_ * 4 + 2], p_[s_ * 4 + 3]);           \
  }                                                                         \
  _Pragma("unroll")                                                         \
  for (int c_ = 0; c_ < 2; c_++) {                                          \
    unsigned a0_ = w_[(2 * c_) * 2 + 0], b0_ = w_[(2 * c_ + 1) * 2 + 0];    \
    unsigned a1_ = w_[(2 * c_) * 2 + 1], b1_ = w_[(2 * c_ + 1) * 2 + 1];    \
    asm volatile("v_permlane32_swap_b32 %0, %1" : "+v"(a0_), "+v"(b0_));    \
    asm volatile("v_permlane32_swap_b32 %0, %1" : "+v"(a1_), "+v"(b1_));    \
    uint4 pw_ = {a0_, a1_, b0_, b1_};                                       \
    bf16x8 pf_ = __builtin_bit_cast(bf16x8, pw_);                           \
    OA = __builtin_amdgcn_mfma_f32_32x32x16_bf16(VF[0 * 2 + c_], pf_, OA, 0, 0, 0); \
    OB = __builtin_amdgcn_mfma_f32_32x32x16_bf16(VF[1 * 2 + c_], pf_, OB, 0, 0, 0); \
  }                                                                         \
} while (0)

__global__ __launch_bounds__(256, 2) void attn_fwd(
    const unsigned short* __restrict__ Q, const unsigned short* __restrict__ K,
    const unsigned short* __restrict__ VT, unsigned short* __restrict__ O) {
  __shared__ alignas(16) unsigned short Kl[2][8192];   // 128 x 64 bf16
  __shared__ alignas(16) unsigned short Vl[2][8192];   // 64 x 128 bf16
  const int tid = threadIdx.x, wid = tid >> 6, lane = tid & 63;
  const int l31 = lane & 31, h = lane >> 5;
  // Complementary-qt pairing (R16-verified): slot 0 gets qt in [8,15],
  // slot 1 the complement -> every CU's two blocks sum to 17 step-units.
  const int xcd = (int)(blockIdx.x & 7), u = (int)(blockIdx.x >> 3);
  const int slot = u >> 5, v = u & 31;
  const int idx = xcd * 32 + v;
  const int bh = idx >> 3;
  const int qt = slot ? (7 - (idx & 7)) : (8 + (idx & 7));
  const unsigned short* Qb = Q + (size_t)bh * SEQ * DHEAD;
  const unsigned short* Kb = K + (size_t)bh * SEQ * DHEAD;
  const unsigned short* Vb = VT + (size_t)bh * DHEAD * SEQ;
  const int q0w = qt * 128 + wid * 32;       // this wave's q base (32 rows)
  bf16x8 qf[4];
#pragma unroll
  for (int dk = 0; dk < 4; dk++)
    qf[dk] = ld_bf16x8(Qb + (size_t)(q0w + l31) * DHEAD + dk * 16 + h * 8);
  f32x16 o0a = {}, o1a = {}, o0b = {}, o1b = {};
  float psum4[4] = {0.f, 0.f, 0.f, 0.f};
  const float cs = 0.18033688011112042f;     // (1/sqrt(64)) * log2(e)
  const int nsteps = qt + 1;                 // 128-key steps

  auto STAGE = [&](unsigned short* Kd, unsigned short* Vd, int s0) {
#pragma unroll
    for (int c = 0; c < 4; c++) {
      int s = c * 256 + tid;
      int row = s >> 3, sl = s & 7;
      int ss = sl ^ (row & 7);
      async16((char*)Kd + (c * 256 + wid * 64) * 16,
              Kb + (size_t)(s0 + row) * DHEAD + ss * 8);
    }
#pragma unroll
    for (int c = 0; c < 4; c++) {
      int s = c * 256 + tid;
      int row = s >> 4, sl = s & 15;
      int ss = sl ^ (row & 7);
      async16((char*)Vd + (c * 256 + wid * 64) * 16,
              Vb + (size_t)row * SEQ + s0 + ss * 8);
    }
  };

  STAGE(Kl[0], Vl[0], 0);
  for (int t = 0; t < nsteps; ++t) {
    if (t + 1 < nsteps) {
      STAGE(Kl[(t + 1) & 1], Vl[(t + 1) & 1], (t + 1) * 128);
      asm volatile("s_waitcnt vmcnt(8)" ::: "memory");   // drain tile t's 8
    } else {
      asm volatile("s_waitcnt vmcnt(0)" ::: "memory");
    }
    __builtin_amdgcn_s_barrier();
    __builtin_amdgcn_sched_barrier(0);
    const unsigned short* Kc = Kl[t & 1];
    const unsigned short* Vc = Vl[t & 1];
    const int s0 = t * 128;
    // number of active 32-key groups this step (wave-uniform)
    const int ng = (s0 <= q0w) ? ((q0w - s0) >> 5) >= 3 ? 4 : (((q0w - s0) >> 5) + 1) : 0;
    if (ng > 0) {
      bf16x8 kfA[4], vfA[4], kfB[4], vfB[4];
      ATTN_READS(kfA, vfA, 0);
      if (ng > 1) { ATTN_READS(kfB, vfB, 1); WAIT_LGKM8_FENCE(); }
      else        { WAIT_LGKM0_FENCE(); }
      ATTN_COMPUTE(kfA, vfA, 0, o0a, o1a);
      if (ng > 1) {
        if (ng > 2) { ATTN_READS(kfA, vfA, 2); WAIT_LGKM8_FENCE(); }
        else        { WAIT_LGKM0_FENCE(); }
        ATTN_COMPUTE(kfB, vfB, 1, o0b, o1b);
        if (ng > 2) {
          if (ng > 3) { ATTN_READS(kfB, vfB, 3); WAIT_LGKM8_FENCE(); }
          else        { WAIT_LGKM0_FENCE(); }
          ATTN_COMPUTE(kfA, vfA, 2, o0a, o1a);
          if (ng > 3) {
            WAIT_LGKM0_FENCE();
            ATTN_COMPUTE(kfB, vfB, 3, o0b, o1b);
          }
        }
      }
    }
    __builtin_amdgcn_sched_barrier(0);
    __builtin_amdgcn_s_barrier();            // all waves done with buf before restage
  }
  // merge split accumulators and denominator partials
  f32x16 o0 = o0a + o0b, o1 = o1a + o1b;
  float psum = (psum4[0] + psum4[1]) + (psum4[2] + psum4[3]);
  psum += __shfl_xor(psum, 32);
  float inv = 1.f / psum;
  // O^T in regs: o[dg][reg] at d = 32dg + (reg&3)+8*(reg>>2)+4h, q = l31.
  // Transpose via per-wave LDS slice (reuse Kl), then coalesced 16B stores.
  unsigned short* slice = (unsigned short*)Kl + wid * 2048;   // 32q x 64d
#pragma unroll
  for (int dg = 0; dg < 2; dg++) {
#pragma unroll
    for (int s = 0; s < 4; s++) {
#pragma unroll
      for (int m = 0; m < 2; m++) {
        float va = (dg ? o1[s * 4 + 2 * m] : o0[s * 4 + 2 * m]) * inv;
        float vb = (dg ? o1[s * 4 + 2 * m + 1] : o0[s * 4 + 2 * m + 1]) * inv;
        unsigned wv = cvt_pk_bf16(va, vb);
        int d = 32 * dg + 8 * s + 4 * h + 2 * m;
        ds_write32(&slice[l31 * 64 + d], wv);
      }
    }
  }
  WAIT_LGKM0_FENCE();
  bf16x8 ov[4];
#pragma unroll
  for (int pss = 0; pss < 4; pss++) {
    int qrow = pss * 8 + (lane >> 3);
    int d0 = (lane & 7) * 8;
    ov[pss] = ds_read16(&slice[qrow * 64 + d0]);
  }
  WAIT_LGKM0_FENCE();
  const int b = bh >> 4, head = bh & 15;
#pragma unroll
  for (int pss = 0; pss < 4; pss++) {
    int qrow = pss * 8 + (lane >> 3);
    int d0 = (lane & 7) * 8;
    *(bf16x8*)(O + ((size_t)b * SEQ + q0w + qrow) * D_MODEL + head * DHEAD + d0) = ov[pss];
  }
}

// ---------------------------------------------------------------------------

extern "C" void kernel_launch(void* const* d_in, const int* in_sizes, int n_in,
                              void* d_out, int out_size, void* d_ws, size_t ws_size,
                              hipStream_t stream) {
  const float* x = (const float*)d_in[0];
  const float* wq = (const float*)d_in[1];
  const float* wk = (const float*)d_in[2];
  const float* wv = (const float*)d_in[3];
  const float* w_proj = (const float*)d_in[4];
  const float* b_proj = (const float*)d_in[5];
  const float* w1 = (const float*)d_in[6];
  const float* b1 = (const float*)d_in[7];
  const float* w2 = (const float*)d_in[8];
  const float* b2 = (const float*)d_in[9];
  const float* ln1g = (const float*)d_in[10];
  const float* ln1b = (const float*)d_in[11];
  const float* ln2g = (const float*)d_in[12];
  const float* ln2b = (const float*)d_in[13];

  char* ws = (char*)d_ws;
  const size_t MB = 1024ull * 1024ull;
  unsigned short* xn = (unsigned short*)(ws + 0);
  unsigned short* Qb = (unsigned short*)(ws + 8 * MB);
  unsigned short* Kb = (unsigned short*)(ws + 16 * MB);
  unsigned short* VTb = (unsigned short*)(ws + 24 * MB);
  unsigned short* aout = (unsigned short*)(ws + 32 * MB);
  unsigned short* hbuf = (unsigned short*)(ws + 40 * MB);
  unsigned short* WqkvT = (unsigned short*)(ws + 72 * MB);
  unsigned short* wprojT = (unsigned short*)(ws + 78 * MB);
  unsigned short* w1T = (unsigned short*)(ws + 80 * MB);
  unsigned short* w2T = (unsigned short*)(ws + 88 * MB);
  float* x1 = (float*)d_out;   // fp32 residual stream lives in d_out

  // fused prep: weight repacks + LN1 (all independent of each other)
  prep_fused<<<dim3(7168), 256, 0, stream>>>(
      wq, wk, wv, w_proj, w1, w2, x, ln1g, ln1b,
      WqkvT, wprojT, w1T, w2T, xn);
  // QKV projection: 8-phase 256x256 GEMM, grid 16x12=192, scatter epilogue
  gemm256_bt<2><<<dim3(192), 512, 0, stream>>>(xn, WqkvT, NTOK, 3072, 1024, 12,
      nullptr, nullptr, Qb, Kb, VTb);
  // attention (512 blocks x 4 waves, complementary-qt CU pairing)
  attn_fwd<<<dim3(512), 256, 0, stream>>>(Qb, Kb, VTb, aout);
  // output projection + residual -> x1 (fp32, in d_out): 128x64 tile
  gemm_n64<0><<<dim3(32, 16), 256, 0, stream>>>(aout, wprojT, NTOK, 1024, 1024,
      b_proj, x, x1);
  // LN2 (reuse xn)
  layernorm_bf16<<<NTOK, 256, 0, stream>>>(x1, ln2g, ln2b, xn);
  // FFN1 + ReLU -> h (bf16): 8-phase 256x256 GEMM, grid 16x16=256
  gemm256_bt<1><<<dim3(256), 512, 0, stream>>>(xn, w1T, NTOK, 4096, 1024, 16,
      b1, hbuf, nullptr, nullptr, nullptr);
  // FFN2 + residual (in-place on d_out): 128x64 tile
  gemm_n64<1><<<dim3(32, 16), 256, 0, stream>>>(hbuf, w2T, NTOK, 1024, 4096,
      b2, x1, (float*)d_out);
}

// Round 24
// 201.361 us; speedup vs baseline: 1.1076x; 1.1076x over previous
//
#include <hip/hip_runtime.h>
#include <hip/hip_bf16.h>
#include <math.h>

// ---------------------------------------------------------------------------
// Transformer block forward (pre-LN), B=2 T=2048 D=1024 H=16 DH=64.
// R23->R24: REVERT to the R18/R21-verified best (201.7/202.2us, reproduced
// twice). R23 (QKV on 8-phase gemm256) regressed to 223us: scatter epilogue
// + co-compiled template codegen perturbation (rule #19) + 0.75 blocks/CU.
// Five QKV tilings bracket ~47us as this family's floor; attention and the
// other GEMMs are at their measured structural plateaus.
// Configuration: prep_fused (repacks+LN1), gemm_p4 QKV (128x128 pipelined,
// counted vmcnt(8), asm LDS), attention v11 (128-key intervals, group
// pipelining, split accumulators, complementary-qt CU pairing, NO setprio),
// gemm_n64 proj/FFN2 (128x64, 3 blocks/CU), gemm256_bt FFN1 (8-phase).
// x1 (fp32 residual) lives in d_out. Workspace layout (96 MB): see R4.
// ---------------------------------------------------------------------------

#define D_MODEL 1024
#define NH 16
#define DHEAD 64
#define SEQ 2048
#define NTOK 4096

typedef __bf16 bf16x8 __attribute__((ext_vector_type(8)));
typedef float f32x4 __attribute__((ext_vector_type(4)));
typedef float f32x16 __attribute__((ext_vector_type(16)));
typedef unsigned short u16x8 __attribute__((ext_vector_type(8)));

__device__ __forceinline__ unsigned short f2b(float f) {
  unsigned u = __builtin_bit_cast(unsigned, f);
  u = u + 0x7fffu + ((u >> 16) & 1u);          // round-nearest-even
  return (unsigned short)(u >> 16);
}

__device__ __forceinline__ bf16x8 ld_bf16x8(const unsigned short* p) {
  u16x8 u = *(const u16x8*)p;
  return __builtin_bit_cast(bf16x8, u);
}

// async global->LDS, 16B per lane; LDS dest is wave-uniform base + lane*16.
__device__ __forceinline__ void async16(void* lds, const void* g) {
  __builtin_amdgcn_global_load_lds(
      (const __attribute__((address_space(1))) unsigned int*)g,
      (__attribute__((address_space(3))) unsigned int*)lds, 16, 0, 0);
}

// inline-asm LDS ops: invisible to the compiler's waitcnt pass, so our
// counted vmcnt/lgkmcnt discipline is authoritative (R8 lesson).
__device__ __forceinline__ bf16x8 ds_read16(const void* p) {
  bf16x8 r;
  unsigned a = (unsigned)(size_t)(const __attribute__((address_space(3))) void*)p;
  asm volatile("ds_read_b128 %0, %1" : "=v"(r) : "v"(a));
  return r;
}
__device__ __forceinline__ void ds_write32(void* p, unsigned v) {
  unsigned a = (unsigned)(size_t)(__attribute__((address_space(3))) void*)p;
  asm volatile("ds_write_b32 %0, %1" :: "v"(a), "v"(v));
}
__device__ __forceinline__ unsigned cvt_pk_bf16(float lo, float hi) {
  unsigned d;
  asm("v_cvt_pk_bf16_f32 %0, %1, %2" : "=v"(d) : "v"(lo), "v"(hi));
  return d;
}
#define WAIT_LGKM0_FENCE() do { \
  asm volatile("s_waitcnt lgkmcnt(0)" ::: "memory"); \
  __builtin_amdgcn_sched_barrier(0); } while (0)
#define WAIT_LGKM8_FENCE() do { \
  asm volatile("s_waitcnt lgkmcnt(8)" ::: "memory"); \
  __builtin_amdgcn_sched_barrier(0); } while (0)

// ---------------------------------------------------------------------------
// prep_fused: [0,768) repack_qkv | [768,1024) w_proj^T | [1024,2048) w1^T |
// [2048,3072) w2^T | [3072,7168) LN1. R18-verified.
// ---------------------------------------------------------------------------
__global__ __launch_bounds__(256) void prep_fused(
    const float* __restrict__ wq, const float* __restrict__ wk,
    const float* __restrict__ wv, const float* __restrict__ w_proj,
    const float* __restrict__ w1, const float* __restrict__ w2,
    const float* __restrict__ x, const float* __restrict__ ln1g,
    const float* __restrict__ ln1b,
    unsigned short* __restrict__ WqkvT, unsigned short* __restrict__ wprojT,
    unsigned short* __restrict__ w1T, unsigned short* __restrict__ w2T,
    unsigned short* __restrict__ xn) {
  __shared__ float tile[64][65];
  __shared__ float ps[4], ps2[4];
  const int bid = blockIdx.x;
  const int tidx = threadIdx.x;

  if (bid < 3072) {
    const float* in;
    unsigned short* outp;
    int r0, c0, R, C;
    if (bid < 768) {
      int t = bid;
      int sel = t >> 8, hh = (t >> 4) & 15, rt = t & 15;
      in = (sel == 0 ? wq : sel == 1 ? wk : wv) + (size_t)hh * D_MODEL * DHEAD;
      int d0 = rt * 64;
      for (int i = 0; i < 16; i++) {
        int idx = i * 256 + tidx;
        int r = idx >> 6, c = idx & 63;
        tile[r][c] = in[(size_t)(d0 + r) * DHEAD + c];
      }
      __syncthreads();
      unsigned short* ob = WqkvT + (size_t)(sel * 1024 + hh * 64) * D_MODEL + d0;
      for (int i = 0; i < 16; i++) {
        int idx = i * 256 + tidx;
        int c = idx >> 6, r = idx & 63;
        ob[(size_t)c * D_MODEL + r] = f2b(tile[r][c]);
      }
      return;
    } else if (bid < 1024) {
      int t = bid - 768;                       // 16x16
      in = w_proj; outp = wprojT; R = 1024; C = 1024;
      r0 = (t & 15) * 64; c0 = (t >> 4) * 64;
    } else if (bid < 2048) {
      int t = bid - 1024;                      // 16x64
      in = w1; outp = w1T; R = 1024; C = 4096;
      r0 = (t & 15) * 64; c0 = (t >> 4) * 64;
    } else {
      int t = bid - 2048;                      // 64x16
      in = w2; outp = w2T; R = 4096; C = 1024;
      r0 = (t & 63) * 64; c0 = (t >> 6) * 64;
    }
    for (int i = 0; i < 16; i++) {
      int idx = i * 256 + tidx;
      int r = idx >> 6, c = idx & 63;
      tile[r][c] = in[(size_t)(r0 + r) * C + c0 + c];
    }
    __syncthreads();
    for (int i = 0; i < 16; i++) {
      int idx = i * 256 + tidx;
      int c = idx >> 6, r = idx & 63;
      outp[(size_t)(c0 + c) * R + r0 + r] = f2b(tile[r][c]);
    }
    return;
  }

  // ---- LN1: one block per row
  const int row = bid - 3072;
  const float4* xr = (const float4*)(x + (size_t)row * D_MODEL);
  float4 v = xr[tidx];
  float s = v.x + v.y + v.z + v.w;
  float s2 = v.x * v.x + v.y * v.y + v.z * v.z + v.w * v.w;
  for (int m = 1; m < 64; m <<= 1) {
    s += __shfl_xor(s, m);
    s2 += __shfl_xor(s2, m);
  }
  int wid = tidx >> 6;
  if ((tidx & 63) == 0) { ps[wid] = s; ps2[wid] = s2; }
  __syncthreads();
  float S = ps[0] + ps[1] + ps[2] + ps[3];
  float S2 = ps2[0] + ps2[1] + ps2[2] + ps2[3];
  float mu = S * (1.f / D_MODEL);
  float var = S2 * (1.f / D_MODEL) - mu * mu;
  float inv = rsqrtf(var + 1e-5f);
  float4 gv = ((const float4*)ln1g)[tidx];
  float4 bv = ((const float4*)ln1b)[tidx];
  ushort4 o;
  o.x = f2b((v.x - mu) * inv * gv.x + bv.x);
  o.y = f2b((v.y - mu) * inv * gv.y + bv.y);
  o.z = f2b((v.z - mu) * inv * gv.z + bv.z);
  o.w = f2b((v.w - mu) * inv * gv.w + bv.w);
  ((ushort4*)(xn + (size_t)row * D_MODEL))[tidx] = o;
}

// ---------------------------------------------------------------------------
// LayerNorm: fp32 [rows][1024] -> bf16, one block per row (LN2).
// ---------------------------------------------------------------------------
__global__ __launch_bounds__(256) void layernorm_bf16(
    const float* __restrict__ x, const float* __restrict__ g,
    const float* __restrict__ bta, unsigned short* __restrict__ out) {
  int row = blockIdx.x;
  int tid = threadIdx.x;
  const float4* xr = (const float4*)(x + (size_t)row * D_MODEL);
  float4 v = xr[tid];
  float s = v.x + v.y + v.z + v.w;
  float s2 = v.x * v.x + v.y * v.y + v.z * v.z + v.w * v.w;
  for (int m = 1; m < 64; m <<= 1) {
    s += __shfl_xor(s, m);
    s2 += __shfl_xor(s2, m);
  }
  __shared__ float ps[4], ps2[4];
  int wid = tid >> 6;
  if ((tid & 63) == 0) { ps[wid] = s; ps2[wid] = s2; }
  __syncthreads();
  float S = ps[0] + ps[1] + ps[2] + ps[3];
  float S2 = ps2[0] + ps2[1] + ps2[2] + ps2[3];
  float mu = S * (1.f / D_MODEL);
  float var = S2 * (1.f / D_MODEL) - mu * mu;
  float inv = rsqrtf(var + 1e-5f);
  float4 gv = ((const float4*)g)[tid];
  float4 bv = ((const float4*)bta)[tid];
  ushort4 o;
  o.x = f2b((v.x - mu) * inv * gv.x + bv.x);
  o.y = f2b((v.y - mu) * inv * gv.y + bv.y);
  o.z = f2b((v.z - mu) * inv * gv.z + bv.z);
  o.w = f2b((v.w - mu) * inv * gv.w + bv.w);
  ((ushort4*)(out + (size_t)row * D_MODEL))[tid] = o;
}

// ---------------------------------------------------------------------------
// GEMM 128x128, 4 waves, pipelined (2 LDS bufs, counted vmcnt(8), asm
// ds_read). MODE 0: outF = acc + bias + resid. MODE 2: QKV scatter.
// R18-verified for QKV.
// ---------------------------------------------------------------------------
template <int MODE>
__global__ __launch_bounds__(256, 2) void gemm_p4(
    const unsigned short* __restrict__ A, const unsigned short* __restrict__ BT,
    int M, int N, int K,
    const float* __restrict__ bias, const float* __restrict__ resid,
    float* __restrict__ outF,
    unsigned short* __restrict__ outQ, unsigned short* __restrict__ outK,
    unsigned short* __restrict__ outV) {
  __shared__ alignas(16) unsigned short lsA[2][128 * 64];
  __shared__ alignas(16) unsigned short lsB[2][128 * 64];
  const int tid = threadIdx.x;
  const int wid = tid >> 6, lane = tid & 63;
  const int lr = lane & 15, lg = lane >> 4;
  const int row0 = blockIdx.x * 128, col0 = blockIdx.y * 128;
  const int wr = (wid >> 1) * 64, wc = (wid & 1) * 64;
  f32x4 acc[4][4] = {};
  const int nk = K >> 6;

  auto STAGE = [&](int bi, int kt) {
    const int k0 = kt << 6;
#pragma unroll
    for (int i = 0; i < 4; i++) {
      int sidx = i * 256 + tid;        // slot index 0..1023
      int r = sidx >> 3, s = sidx & 7;
      int ss = s ^ (r & 7);            // inverse-swizzled source slot
      async16((char*)lsA[bi] + (i * 256 + wid * 64) * 16,
              A + (size_t)(row0 + r) * K + k0 + ss * 8);
      async16((char*)lsB[bi] + (i * 256 + wid * 64) * 16,
              BT + (size_t)(col0 + r) * K + k0 + ss * 8);
    }
  };

  STAGE(0, 0);
  for (int kt = 0; kt < nk; ++kt) {
    const int cur = kt & 1;
    if (kt + 1 < nk) {
      STAGE(cur ^ 1, kt + 1);
      asm volatile("s_waitcnt vmcnt(8)" ::: "memory");   // drain tile kt only
    } else {
      asm volatile("s_waitcnt vmcnt(0)" ::: "memory");
    }
    __builtin_amdgcn_s_barrier();
    __builtin_amdgcn_sched_barrier(0);
#pragma unroll
    for (int kk = 0; kk < 2; ++kk) {
      bf16x8 af[4], bfr[4];
#pragma unroll
      for (int m = 0; m < 4; m++) {
        int r = wr + m * 16 + lr;
        int sw = (kk * 4 + lg) ^ (r & 7);
        af[m] = ds_read16((const char*)lsA[cur] + r * 128 + sw * 16);
      }
#pragma unroll
      for (int n = 0; n < 4; n++) {
        int r = wc + n * 16 + lr;
        int sw = (kk * 4 + lg) ^ (r & 7);
        bfr[n] = ds_read16((const char*)lsB[cur] + r * 128 + sw * 16);
      }
      WAIT_LGKM0_FENCE();
      __builtin_amdgcn_s_setprio(1);
#pragma unroll
      for (int m = 0; m < 4; m++)
#pragma unroll
        for (int n = 0; n < 4; n++)
          acc[m][n] = __builtin_amdgcn_mfma_f32_16x16x32_bf16(af[m], bfr[n], acc[m][n], 0, 0, 0);
      __builtin_amdgcn_s_setprio(0);
    }
    __builtin_amdgcn_sched_barrier(0);
    __builtin_amdgcn_s_barrier();      // all done reading buf[cur] before restage
  }
#pragma unroll
  for (int m = 0; m < 4; m++) {
#pragma unroll
    for (int n = 0; n < 4; n++) {
#pragma unroll
      for (int r2 = 0; r2 < 4; r2++) {
        int row = row0 + wr + m * 16 + lg * 4 + r2;
        int col = col0 + wc + n * 16 + lr;
        float v = acc[m][n][r2];
        if constexpr (MODE == 0) {
          v += bias[col] + resid[(size_t)row * N + col];
          outF[(size_t)row * N + col] = v;
        } else {
          int sel = col >> 10, jj = col & 1023, hh = jj >> 6, dh = jj & 63;
          int b = row >> 11, t = row & 2047;
          size_t bh = (size_t)(b * NH + hh);
          if (sel == 0)      outQ[(bh * SEQ + t) * DHEAD + dh] = f2b(v);
          else if (sel == 1) outK[(bh * SEQ + t) * DHEAD + dh] = f2b(v);
          else               outV[(bh * DHEAD + dh) * SEQ + t] = f2b(v);  // transposed
        }
      }
    }
  }
}

// ---------------------------------------------------------------------------
// GEMM 128x64, 4 waves (2Mx2N, wave tile 64x32), pipelined (2 LDS bufs,
// counted vmcnt(6), asm ds_read). 48KB LDS -> 3 blocks/CU (R17-verified).
// For proj (TAG 0) and FFN2 (TAG 1). Epilogue: outF = acc + bias + resid.
// ---------------------------------------------------------------------------
template <int TAG>
__global__ __launch_bounds__(256, 3) void gemm_n64(
    const unsigned short* __restrict__ A, const unsigned short* __restrict__ BT,
    int M, int N, int K,
    const float* __restrict__ bias, const float* __restrict__ resid,
    float* __restrict__ outF) {
  __shared__ alignas(16) unsigned short lsA[2][128 * 64];   // 16KB each
  __shared__ alignas(16) unsigned short lsB[2][64 * 64];    // 8KB each
  const int tid = threadIdx.x;
  const int wid = tid >> 6, lane = tid & 63;
  const int lr = lane & 15, lg = lane >> 4;
  const int row0 = blockIdx.x * 128, col0 = blockIdx.y * 64;
  const int wr = (wid >> 1) * 64, wc = (wid & 1) * 32;
  f32x4 acc[4][2] = {};
  const int nk = K >> 6;

  auto STAGE = [&](int bi, int kt) {
    const int k0 = kt << 6;
#pragma unroll
    for (int i = 0; i < 4; i++) {      // A: 1024 slots of 16B
      int sidx = i * 256 + tid;
      int r = sidx >> 3, s = sidx & 7;
      int ss = s ^ (r & 7);
      async16((char*)lsA[bi] + (i * 256 + wid * 64) * 16,
              A + (size_t)(row0 + r) * K + k0 + ss * 8);
    }
#pragma unroll
    for (int i = 0; i < 2; i++) {      // B: 512 slots of 16B
      int sidx = i * 256 + tid;
      int r = sidx >> 3, s = sidx & 7;
      int ss = s ^ (r & 7);
      async16((char*)lsB[bi] + (i * 256 + wid * 64) * 16,
              BT + (size_t)(col0 + r) * K + k0 + ss * 8);
    }
  };

  STAGE(0, 0);
  for (int kt = 0; kt < nk; ++kt) {
    const int cur = kt & 1;
    if (kt + 1 < nk) {
      STAGE(cur ^ 1, kt + 1);
      asm volatile("s_waitcnt vmcnt(6)" ::: "memory");   // drain tile kt's 6 only
    } else {
      asm volatile("s_waitcnt vmcnt(0)" ::: "memory");
    }
    __builtin_amdgcn_s_barrier();
    __builtin_amdgcn_sched_barrier(0);
#pragma unroll
    for (int kk = 0; kk < 2; ++kk) {
      bf16x8 af[4], bfr[2];
#pragma unroll
      for (int m = 0; m < 4; m++) {
        int r = wr + m * 16 + lr;
        int sw = (kk * 4 + lg) ^ (r & 7);
        af[m] = ds_read16((const char*)lsA[cur] + r * 128 + sw * 16);
      }
#pragma unroll
      for (int n = 0; n < 2; n++) {
        int r = wc + n * 16 + lr;
        int sw = (kk * 4 + lg) ^ (r & 7);
        bfr[n] = ds_read16((const char*)lsB[cur] + r * 128 + sw * 16);
      }
      WAIT_LGKM0_FENCE();
      __builtin_amdgcn_s_setprio(1);
#pragma unroll
      for (int m = 0; m < 4; m++)
#pragma unroll
        for (int n = 0; n < 2; n++)
          acc[m][n] = __builtin_amdgcn_mfma_f32_16x16x32_bf16(af[m], bfr[n], acc[m][n], 0, 0, 0);
      __builtin_amdgcn_s_setprio(0);
    }
    __builtin_amdgcn_sched_barrier(0);
    __builtin_amdgcn_s_barrier();      // all done reading buf[cur] before restage
  }
#pragma unroll
  for (int m = 0; m < 4; m++) {
#pragma unroll
    for (int n = 0; n < 2; n++) {
#pragma unroll
      for (int r2 = 0; r2 < 4; r2++) {
        int row = row0 + wr + m * 16 + lg * 4 + r2;
        int col = col0 + wc + n * 16 + lr;
        float v = acc[m][n][r2] + bias[col] + resid[(size_t)row * N + col];
        outF[(size_t)row * N + col] = v;
      }
    }
  }
}

// ---------------------------------------------------------------------------
// GEMM 256x256, 8-phase (T3+T4+T5), for FFN1 ONLY — asm fragment reads.
// ---------------------------------------------------------------------------
__global__ __launch_bounds__(512, 2) void gemm256_bt(
    const unsigned short* __restrict__ A, const unsigned short* __restrict__ BT,
    int M, int N, int K, int ntn,
    const float* __restrict__ bias, unsigned short* __restrict__ outB) {
  __shared__ alignas(16) unsigned short ls[2][2][2][256 * 32];
  const int tid = threadIdx.x;
  const int wid = tid >> 6, lane = tid & 63;
  const int lr = lane & 15, lg = lane >> 4;
  const int nwg = gridDim.x;
  const int wg = (blockIdx.x & 7) * (nwg >> 3) + (blockIdx.x >> 3);
  const int row0 = (wg / ntn) * 256, col0 = (wg % ntn) * 256;
  const int mbase = (wid >> 2) * 128;
  const int nbase = (wid & 3) * 64;

  f32x4 acc[8][4] = {};

  auto STAGE = [&](int buf, int kh, int ab, int kt) {
    const unsigned short* src = ab ? (BT + (size_t)col0 * K) : (A + (size_t)row0 * K);
    const int kbase = kt * 64 + kh * 32;
    unsigned short* dst0 = &ls[buf][kh][ab][0];
#pragma unroll
    for (int c = 0; c < 2; c++) {
      int s = c * 512 + tid;
      int row = s >> 2, c2 = s & 3;
      int ss = c2 ^ ((row >> 1) & 3);
      async16(dst0 + (size_t)(c * 512 + wid * 64) * 8,
              src + (size_t)row * K + kbase + ss * 8);
    }
  };
  auto LDA = [&](bf16x8* a, int buf, int kk, int mh) {
#pragma unroll
    for (int i = 0; i < 4; i++) {
      int mrow = mbase + (mh * 4 + i) * 16 + lr;
      int ch = lg ^ ((mrow >> 1) & 3);
      a[i] = ds_read16(&ls[buf][kk][0][mrow * 32 + ch * 8]);
    }
  };
  auto LDB = [&](bf16x8* b, int buf, int kk) {
#pragma unroll
    for (int i = 0; i < 4; i++) {
      int brow = nbase + i * 16 + lr;
      int ch = lg ^ ((brow >> 1) & 3);
      b[i] = ds_read16(&ls[buf][kk][1][brow * 32 + ch * 8]);
    }
  };

  const int nk = K >> 6;
  STAGE(0, 0, 0, 0); STAGE(0, 0, 1, 0); STAGE(0, 1, 0, 0); STAGE(0, 1, 1, 0);
  asm volatile("s_waitcnt vmcnt(4)" ::: "memory");
  __builtin_amdgcn_s_barrier();

  for (int t = 0; t < nk; ++t) {
    const int cur = t & 1, nxt = cur ^ 1;
    const bool haveNext = (t + 1 < nk);
    bf16x8 a[4], b[4];
    // ---- ph1
    LDA(a, cur, 0, 0); LDB(b, cur, 0);
    if (haveNext) STAGE(nxt, 0, 0, t + 1);
    __builtin_amdgcn_s_barrier();
    WAIT_LGKM0_FENCE();
    __builtin_amdgcn_s_setprio(1);
#pragma unroll
    for (int i = 0; i < 4; i++)
#pragma unroll
      for (int j = 0; j < 4; j++)
        acc[i][j] = __builtin_amdgcn_mfma_f32_16x16x32_bf16(a[i], b[j], acc[i][j], 0, 0, 0);
    __builtin_amdgcn_s_setprio(0);
    __builtin_amdgcn_s_barrier();
    // ---- ph2
    LDA(a, cur, 0, 1);
    if (haveNext) {
      STAGE(nxt, 0, 1, t + 1);
      asm volatile("s_waitcnt vmcnt(4)" ::: "memory");
    } else {
      asm volatile("s_waitcnt vmcnt(0)" ::: "memory");
    }
    __builtin_amdgcn_s_barrier();
    WAIT_LGKM0_FENCE();
    __builtin_amdgcn_s_setprio(1);
#pragma unroll
    for (int i = 0; i < 4; i++)
#pragma unroll
      for (int j = 0; j < 4; j++)
        acc[4 + i][j] = __builtin_amdgcn_mfma_f32_16x16x32_bf16(a[i], b[j], acc[4 + i][j], 0, 0, 0);
    __builtin_amdgcn_s_setprio(0);
    __builtin_amdgcn_s_barrier();
    // ---- ph3
    LDA(a, cur, 1, 0); LDB(b, cur, 1);
    if (haveNext) STAGE(nxt, 1, 0, t + 1);
    __builtin_amdgcn_s_barrier();
    WAIT_LGKM0_FENCE();
    __builtin_amdgcn_s_setprio(1);
#pragma unroll
    for (int i = 0; i < 4; i++)
#pragma unroll
      for (int j = 0; j < 4; j++)
        acc[i][j] = __builtin_amdgcn_mfma_f32_16x16x32_bf16(a[i], b[j], acc[i][j], 0, 0, 0);
    __builtin_amdgcn_s_setprio(0);
    __builtin_amdgcn_s_barrier();
    // ---- ph4
    LDA(a, cur, 1, 1);
    if (haveNext) {
      STAGE(nxt, 1, 1, t + 1);
      asm volatile("s_waitcnt vmcnt(4)" ::: "memory");
    }
    __builtin_amdgcn_s_barrier();
    WAIT_LGKM0_FENCE();
    __builtin_amdgcn_s_setprio(1);
#pragma unroll
    for (int i = 0; i < 4; i++)
#pragma unroll
      for (int j = 0; j < 4; j++)
        acc[4 + i][j] = __builtin_amdgcn_mfma_f32_16x16x32_bf16(a[i], b[j], acc[4 + i][j], 0, 0, 0);
    __builtin_amdgcn_s_setprio(0);
    __builtin_amdgcn_s_barrier();
  }
#pragma unroll
  for (int mi = 0; mi < 8; mi++) {
#pragma unroll
    for (int ni = 0; ni < 4; ni++) {
#pragma unroll
      for (int r2 = 0; r2 < 4; r2++) {
        int row = row0 + mbase + mi * 16 + lg * 4 + r2;
        int col = col0 + nbase + ni * 16 + lr;
        float v = acc[mi][ni][r2] + bias[col];
        outB[(size_t)row * N + col] = f2b(fmaxf(v, 0.f));
      }
    }
  }
}

// ---------------------------------------------------------------------------
// Causal flash attention v11 (R16/R18-verified): 128-key intervals, group
// pipelining, split accumulators, complementary-qt CU pairing. NO setprio.
// ---------------------------------------------------------------------------

// read group G's K/V fragments into KF[4], VF[4]
#define ATTN_READS(KF, VF, G) do {                                          \
  int krow_ = 32 * (G) + l31;                                               \
  int ksw_ = krow_ & 7;                                                     \
  _Pragma("unroll")                                                         \
  for (int dk_ = 0; dk_ < 4; dk_++) {                                       \
    int ch_ = (2 * dk_ + h) ^ ksw_;                                         \
    KF[dk_] = ds_read16((const char*)Kc + krow_ * 128 + ch_ * 16);          \
  }                                                                         \
  _Pragma("unroll")                                                         \
  for (int dg_ = 0; dg_ < 2; dg_++) {                                       \
    int vrow_ = 32 * dg_ + l31;                                             \
    int vsw_ = vrow_ & 7;                                                   \
    _Pragma("unroll")                                                       \
    for (int c_ = 0; c_ < 2; c_++) {                                        \
      int kk_ = 2 * (G) + c_;                                               \
      int ch_ = (2 * kk_ + h) ^ vsw_;                                       \
      VF[dg_ * 2 + c_] = ds_read16((const char*)Vc + vrow_ * 256 + ch_ * 16); \
    }                                                                       \
  }                                                                         \
} while (0)

// compute group G from KF/VF into accumulators OA(d0-31)/OB(d32-63)
#define ATTN_COMPUTE(KF, VF, G, OA, OB) do {                                \
  const int s0g_ = s0 + 32 * (G);                                           \
  const bool needMask_ = (s0g_ == q0w);                                     \
  f32x16 st_ = {};                                                          \
  _Pragma("unroll")                                                         \
  for (int dk_ = 0; dk_ < 4; dk_++)                                         \
    st_ = __builtin_amdgcn_mfma_f32_32x32x16_bf16(KF[dk_], qf[dk_], st_, 0, 0, 0); \
  float p_[16];                                                             \
  _Pragma("unroll")                                                         \
  for (int reg_ = 0; reg_ < 16; reg_++) {                                   \
    float xx_ = st_[reg_] * cs;                                             \
    if (needMask_) {                                                        \
      int kg_ = s0g_ + (reg_ & 3) + 8 * (reg_ >> 2) + 4 * h;                \
      if (kg_ > q0w + l31) xx_ = -INFINITY;                                 \
    }                                                                       \
    float e_ = __builtin_amdgcn_exp2f(xx_);                                 \
    p_[reg_] = e_;                                                          \
    psum4[reg_ & 3] += e_;                                                  \
  }                                                                         \
  unsigned w_[8];                                                           \
  _Pragma("unroll")                                                         \
  for (int s_ = 0; s_ < 4; s_++) {                                          \
    w_[s_ * 2 + 0] = cvt_pk_bf16(p_[s_ * 4 + 0], p_[s_ * 4 + 1]);           \
    w_[s_ * 2 + 1] = cvt_pk_bf16(p_[s_ * 4 + 2], p_[s_ * 4 + 3]);           \
  }                                                                         \
  _Pragma("unroll")                                                         \
  for (int c_ = 0; c_ < 2; c_++) {                                          \
    unsigned a0_ = w_[(2 * c_) * 2 + 0], b0_ = w_[(2 * c_ + 1) * 2 + 0];    \
    unsigned a1_ = w_[(2 * c_) * 2 + 1], b1_ = w_[(2 * c_ + 1) * 2 + 1];    \
    asm volatile("v_permlane32_swap_b32 %0, %1" : "+v"(a0_), "+v"(b0_));    \
    asm volatile("v_permlane32_swap_b32 %0, %1" : "+v"(a1_), "+v"(b1_));    \
    uint4 pw_ = {a0_, a1_, b0_, b1_};                                       \
    bf16x8 pf_ = __builtin_bit_cast(bf16x8, pw_);                           \
    OA = __builtin_amdgcn_mfma_f32_32x32x16_bf16(VF[0 * 2 + c_], pf_, OA, 0, 0, 0); \
    OB = __builtin_amdgcn_mfma_f32_32x32x16_bf16(VF[1 * 2 + c_], pf_, OB, 0, 0, 0); \
  }                                                                         \
} while (0)

__global__ __launch_bounds__(256, 2) void attn_fwd(
    const unsigned short* __restrict__ Q, const unsigned short* __restrict__ K,
    const unsigned short* __restrict__ VT, unsigned short* __restrict__ O) {
  __shared__ alignas(16) unsigned short Kl[2][8192];   // 128 x 64 bf16
  __shared__ alignas(16) unsigned short Vl[2][8192];   // 64 x 128 bf16
  const int tid = threadIdx.x, wid = tid >> 6, lane = tid & 63;
  const int l31 = lane & 31, h = lane >> 5;
  // Complementary-qt pairing (R16-verified): slot 0 gets qt in [8,15],
  // slot 1 the complement -> every CU's two blocks sum to 17 step-units.
  const int xcd = (int)(blockIdx.x & 7), u = (int)(blockIdx.x >> 3);
  const int slot = u >> 5, v = u & 31;
  const int idx = xcd * 32 + v;
  const int bh = idx >> 3;
  const int qt = slot ? (7 - (idx & 7)) : (8 + (idx & 7));
  const unsigned short* Qb = Q + (size_t)bh * SEQ * DHEAD;
  const unsigned short* Kb = K + (size_t)bh * SEQ * DHEAD;
  const unsigned short* Vb = VT + (size_t)bh * DHEAD * SEQ;
  const int q0w = qt * 128 + wid * 32;       // this wave's q base (32 rows)
  bf16x8 qf[4];
#pragma unroll
  for (int dk = 0; dk < 4; dk++)
    qf[dk] = ld_bf16x8(Qb + (size_t)(q0w + l31) * DHEAD + dk * 16 + h * 8);
  f32x16 o0a = {}, o1a = {}, o0b = {}, o1b = {};
  float psum4[4] = {0.f, 0.f, 0.f, 0.f};
  const float cs = 0.18033688011112042f;     // (1/sqrt(64)) * log2(e)
  const int nsteps = qt + 1;                 // 128-key steps

  auto STAGE = [&](unsigned short* Kd, unsigned short* Vd, int s0) {
#pragma unroll
    for (int c = 0; c < 4; c++) {
      int s = c * 256 + tid;
      int row = s >> 3, sl = s & 7;
      int ss = sl ^ (row & 7);
      async16((char*)Kd + (c * 256 + wid * 64) * 16,
              Kb + (size_t)(s0 + row) * DHEAD + ss * 8);
    }
#pragma unroll
    for (int c = 0; c < 4; c++) {
      int s = c * 256 + tid;
      int row = s >> 4, sl = s & 15;
      int ss = sl ^ (row & 7);
      async16((char*)Vd + (c * 256 + wid * 64) * 16,
              Vb + (size_t)row * SEQ + s0 + ss * 8);
    }
  };

  STAGE(Kl[0], Vl[0], 0);
  for (int t = 0; t < nsteps; ++t) {
    if (t + 1 < nsteps) {
      STAGE(Kl[(t + 1) & 1], Vl[(t + 1) & 1], (t + 1) * 128);
      asm volatile("s_waitcnt vmcnt(8)" ::: "memory");   // drain tile t's 8
    } else {
      asm volatile("s_waitcnt vmcnt(0)" ::: "memory");
    }
    __builtin_amdgcn_s_barrier();
    __builtin_amdgcn_sched_barrier(0);
    const unsigned short* Kc = Kl[t & 1];
    const unsigned short* Vc = Vl[t & 1];
    const int s0 = t * 128;
    // number of active 32-key groups this step (wave-uniform)
    const int ng = (s0 <= q0w) ? ((q0w - s0) >> 5) >= 3 ? 4 : (((q0w - s0) >> 5) + 1) : 0;
    if (ng > 0) {
      bf16x8 kfA[4], vfA[4], kfB[4], vfB[4];
      ATTN_READS(kfA, vfA, 0);
      if (ng > 1) { ATTN_READS(kfB, vfB, 1); WAIT_LGKM8_FENCE(); }
      else        { WAIT_LGKM0_FENCE(); }
      ATTN_COMPUTE(kfA, vfA, 0, o0a, o1a);
      if (ng > 1) {
        if (ng > 2) { ATTN_READS(kfA, vfA, 2); WAIT_LGKM8_FENCE(); }
        else        { WAIT_LGKM0_FENCE(); }
        ATTN_COMPUTE(kfB, vfB, 1, o0b, o1b);
        if (ng > 2) {
          if (ng > 3) { ATTN_READS(kfB, vfB, 3); WAIT_LGKM8_FENCE(); }
          else        { WAIT_LGKM0_FENCE(); }
          ATTN_COMPUTE(kfA, vfA, 2, o0a, o1a);
          if (ng > 3) {
            WAIT_LGKM0_FENCE();
            ATTN_COMPUTE(kfB, vfB, 3, o0b, o1b);
          }
        }
      }
    }
    __builtin_amdgcn_sched_barrier(0);
    __builtin_amdgcn_s_barrier();            // all waves done with buf before restage
  }
  // merge split accumulators and denominator partials
  f32x16 o0 = o0a + o0b, o1 = o1a + o1b;
  float psum = (psum4[0] + psum4[1]) + (psum4[2] + psum4[3]);
  psum += __shfl_xor(psum, 32);
  float inv = 1.f / psum;
  // O^T in regs: o[dg][reg] at d = 32dg + (reg&3)+8*(reg>>2)+4h, q = l31.
  // Transpose via per-wave LDS slice (reuse Kl), then coalesced 16B stores.
  unsigned short* slice = (unsigned short*)Kl + wid * 2048;   // 32q x 64d
#pragma unroll
  for (int dg = 0; dg < 2; dg++) {
#pragma unroll
    for (int s = 0; s < 4; s++) {
#pragma unroll
      for (int m = 0; m < 2; m++) {
        float va = (dg ? o1[s * 4 + 2 * m] : o0[s * 4 + 2 * m]) * inv;
        float vb = (dg ? o1[s * 4 + 2 * m + 1] : o0[s * 4 + 2 * m + 1]) * inv;
        unsigned wv = cvt_pk_bf16(va, vb);
        int d = 32 * dg + 8 * s + 4 * h + 2 * m;
        ds_write32(&slice[l31 * 64 + d], wv);
      }
    }
  }
  WAIT_LGKM0_FENCE();
  bf16x8 ov[4];
#pragma unroll
  for (int pss = 0; pss < 4; pss++) {
    int qrow = pss * 8 + (lane >> 3);
    int d0 = (lane & 7) * 8;
    ov[pss] = ds_read16(&slice[qrow * 64 + d0]);
  }
  WAIT_LGKM0_FENCE();
  const int b = bh >> 4, head = bh & 15;
#pragma unroll
  for (int pss = 0; pss < 4; pss++) {
    int qrow = pss * 8 + (lane >> 3);
    int d0 = (lane & 7) * 8;
    *(bf16x8*)(O + ((size_t)b * SEQ + q0w + qrow) * D_MODEL + head * DHEAD + d0) = ov[pss];
  }
}

// ---------------------------------------------------------------------------

extern "C" void kernel_launch(void* const* d_in, const int* in_sizes, int n_in,
                              void* d_out, int out_size, void* d_ws, size_t ws_size,
                              hipStream_t stream) {
  const float* x = (const float*)d_in[0];
  const float* wq = (const float*)d_in[1];
  const float* wk = (const float*)d_in[2];
  const float* wv = (const float*)d_in[3];
  const float* w_proj = (const float*)d_in[4];
  const float* b_proj = (const float*)d_in[5];
  const float* w1 = (const float*)d_in[6];
  const float* b1 = (const float*)d_in[7];
  const float* w2 = (const float*)d_in[8];
  const float* b2 = (const float*)d_in[9];
  const float* ln1g = (const float*)d_in[10];
  const float* ln1b = (const float*)d_in[11];
  const float* ln2g = (const float*)d_in[12];
  const float* ln2b = (const float*)d_in[13];

  char* ws = (char*)d_ws;
  const size_t MB = 1024ull * 1024ull;
  unsigned short* xn = (unsigned short*)(ws + 0);
  unsigned short* Qb = (unsigned short*)(ws + 8 * MB);
  unsigned short* Kb = (unsigned short*)(ws + 16 * MB);
  unsigned short* VTb = (unsigned short*)(ws + 24 * MB);
  unsigned short* aout = (unsigned short*)(ws + 32 * MB);
  unsigned short* hbuf = (unsigned short*)(ws + 40 * MB);
  unsigned short* WqkvT = (unsigned short*)(ws + 72 * MB);
  unsigned short* wprojT = (unsigned short*)(ws + 78 * MB);
  unsigned short* w1T = (unsigned short*)(ws + 80 * MB);
  unsigned short* w2T = (unsigned short*)(ws + 88 * MB);
  float* x1 = (float*)d_out;   // fp32 residual stream lives in d_out

  // fused prep: weight repacks + LN1 (all independent of each other)
  prep_fused<<<dim3(7168), 256, 0, stream>>>(
      wq, wk, wv, w_proj, w1, w2, x, ln1g, ln1b,
      WqkvT, wprojT, w1T, w2T, xn);
  // QKV projection (pipelined gemm_p4, R18 config), scatter epilogue
  gemm_p4<2><<<dim3(32, 24), 256, 0, stream>>>(xn, WqkvT, NTOK, 3072, 1024,
      nullptr, nullptr, nullptr, Qb, Kb, VTb);
  // attention (512 blocks x 4 waves, complementary-qt CU pairing)
  attn_fwd<<<dim3(512), 256, 0, stream>>>(Qb, Kb, VTb, aout);
  // output projection + residual -> x1 (fp32, in d_out): 128x64 tile
  gemm_n64<0><<<dim3(32, 16), 256, 0, stream>>>(aout, wprojT, NTOK, 1024, 1024,
      b_proj, x, x1);
  // LN2 (reuse xn)
  layernorm_bf16<<<NTOK, 256, 0, stream>>>(x1, ln2g, ln2b, xn);
  // FFN1 + ReLU -> h (bf16): 8-phase 256x256 GEMM, grid 16x16=256
  gemm256_bt<<<dim3(256), 512, 0, stream>>>(xn, w1T, NTOK, 4096, 1024, 16,
      b1, hbuf);
  // FFN2 + residual (in-place on d_out): 128x64 tile
  gemm_n64<1><<<dim3(32, 16), 256, 0, stream>>>(hbuf, w2T, NTOK, 1024, 4096,
      b2, x1, (float*)d_out);
}